// Round 1
// baseline (536.978 us; speedup 1.0000x reference)
//
#include <hip/hip_runtime.h>
#include <cstdint>
#include <cstddef>

#define BB_ 64
#define DD_ 2048
#define HH_ 1024

// d_out layout: ht (B*H) | ct (B*H*H) | nt (B*H) | mt (B*H)
#define OFF_HT ((size_t)0)
#define OFF_CT ((size_t)BB_ * HH_)
#define OFF_NT (OFF_CT + (size_t)BB_ * HH_ * HH_)
#define OFF_MT (OFF_NT + (size_t)BB_ * HH_)

typedef float floatx4 __attribute__((ext_vector_type(4)));

// ---------------------------------------------------------------------------
// Kernel 1: six projections z_w[b][h] = sum_d x[b,d] * W_w[d,h], split-K.
// Each block: one (w, k-chunk, 64-wide h tile). 256 threads = 4 waves; each
// wave covers 64 h lanes and a 16-row b slab. x accesses are wave-uniform
// (readfirstlane'd sub id) -> scalar loads; W streamed coalesced.
// ---------------------------------------------------------------------------
__global__ __launch_bounds__(256) void proj_kernel(
    const float* __restrict__ x,
    const float* __restrict__ W0, const float* __restrict__ W1,
    const float* __restrict__ W2, const float* __restrict__ W3,
    const float* __restrict__ W4, const float* __restrict__ W5,
    float* __restrict__ part, int splitk)
{
    const int chunk_sz = DD_ / splitk;
    const int bid = blockIdx.x;
    const int w   = bid / (splitk * 16);
    const int rem = bid % (splitk * 16);
    const int ch  = rem / 16;
    const int ht  = rem % 16;
    const int lane = threadIdx.x & 63;
    const int sub  = __builtin_amdgcn_readfirstlane(threadIdx.x >> 6);
    const int h = ht * 64 + lane;
    const int b_base = sub * 16;

    const float* __restrict__ Wp;
    switch (w) {
        case 0: Wp = W0; break; case 1: Wp = W1; break; case 2: Wp = W2; break;
        case 3: Wp = W3; break; case 4: Wp = W4; break; default: Wp = W5; break;
    }

    float acc[16];
#pragma unroll
    for (int i = 0; i < 16; ++i) acc[i] = 0.f;

    const int d0 = ch * chunk_sz;
    const float* __restrict__ xb = x + (size_t)b_base * DD_;

    for (int d = d0; d < d0 + chunk_sz; d += 4) {
        const float w0 = Wp[(size_t)(d + 0) * HH_ + h];
        const float w1 = Wp[(size_t)(d + 1) * HH_ + h];
        const float w2 = Wp[(size_t)(d + 2) * HH_ + h];
        const float w3 = Wp[(size_t)(d + 3) * HH_ + h];
#pragma unroll
        for (int bb = 0; bb < 16; ++bb) {
            const float* __restrict__ xr = xb + (size_t)bb * DD_ + d;
            acc[bb] += xr[0] * w0 + xr[1] * w1 + xr[2] * w2 + xr[3] * w3;
        }
    }

#pragma unroll
    for (int bb = 0; bb < 16; ++bb) {
        part[(((size_t)w * splitk + ch) * BB_ + (b_base + bb)) * HH_ + h] = acc[bb];
    }
}

// ---------------------------------------------------------------------------
// Kernel 2: reduce split-K partials, compute gates & pointwise outputs.
// Writes mt, nt to d_out; stages ft, vt, kt, qt, ot in ws; accumulates
// normalize_inner = sum_h nt*qt into denom_raw[b] via one atomicAdd/block.
// Grid: (H/256, B).
// ---------------------------------------------------------------------------
__global__ __launch_bounds__(256) void gate_kernel(
    const float* __restrict__ part,
    const float* __restrict__ bi, const float* __restrict__ bf_,
    const float* __restrict__ bo, const float* __restrict__ bq,
    const float* __restrict__ bk, const float* __restrict__ bv,
    const float* __restrict__ n_in, const float* __restrict__ m_in,
    float* __restrict__ out,
    float* __restrict__ gF, float* __restrict__ gV, float* __restrict__ gK,
    float* __restrict__ gQ, float* __restrict__ gO,
    float* __restrict__ denom_raw, int splitk)
{
    const int b = blockIdx.y;
    const int h = blockIdx.x * 256 + threadIdx.x;
    const size_t bh = (size_t)b * HH_ + h;

    float z[6];
#pragma unroll
    for (int w = 0; w < 6; ++w) {
        float s = 0.f;
        for (int ch = 0; ch < splitk; ++ch)
            s += part[(((size_t)w * splitk + ch) * BB_ + b) * HH_ + h];
        z[w] = s;
    }

    const float i_t = z[0] + bi[h];
    const float f_t = z[1] + bf_[h];
    const float o_t = z[2] + bo[h];
    const float q   = z[3] + bq[h];
    const float k   = (z[4] + bk[h]) * 0.03125f;   // 1/sqrt(1024)
    const float v   = z[5] + bv[h];

    const float ft = 1.f / (1.f + expf(-f_t));
    const float ot = 1.f / (1.f + expf(-o_t));
    // log(sigmoid(f)) stable in both tails
    const float lf = (f_t > 0.f) ? -log1pf(expf(-f_t)) : (f_t - log1pf(expf(f_t)));
    const float mt = fmaxf(lf + m_in[bh], i_t);
    const float ip = expf(i_t - mt);               // <= 1 by construction
    const float nt = ft * n_in[bh] + ip * k;

    out[OFF_MT + bh] = mt;
    out[OFF_NT + bh] = nt;
    gF[bh] = ft; gV[bh] = v; gK[bh] = k; gQ[bh] = q; gO[bh] = ot;

    // block-level reduction of nt*q, one atomic per block
    float val = nt * q;
#pragma unroll
    for (int off = 32; off; off >>= 1)
        val += __shfl_down(val, off, 64);

    __shared__ float red[4];
    const int lane = threadIdx.x & 63;
    const int wv   = threadIdx.x >> 6;
    if (lane == 0) red[wv] = val;
    __syncthreads();
    if (threadIdx.x == 0) {
        atomicAdd(&denom_raw[b], red[0] + red[1] + red[2] + red[3]);
    }
}

// ---------------------------------------------------------------------------
// Kernel 3 (dominant): ct[b,i,:] = ft[b,i]*c[b,i,:] + vt[b,i]*kt[b,:],
// fused with h_tilde[b,i] = sum_j ct[b,i,j]*qt[b,j]; ht = ot*h_tilde/denom.
// One wave per row (b,i); float4 nontemporal streaming of c / ct.
// ---------------------------------------------------------------------------
__global__ __launch_bounds__(256) void state_kernel(
    const float* __restrict__ c,
    const float* __restrict__ gF, const float* __restrict__ gV,
    const float* __restrict__ gK, const float* __restrict__ gQ,
    const float* __restrict__ gO, const float* __restrict__ denom_raw,
    float* __restrict__ out)
{
    const int wv   = threadIdx.x >> 6;
    const int lane = threadIdx.x & 63;
    const int r = blockIdx.x * 4 + wv;       // global row = b*H + i
    const int b = r >> 10;

    const float ftv = gF[r];
    const float vtv = gV[r];
    float dn = denom_raw[b];
    dn = fmaxf(fabsf(dn), 1.f);

    const floatx4* __restrict__ c4  = (const floatx4*)(c + (size_t)r * HH_);
    floatx4* __restrict__       ct4 = (floatx4*)(out + OFF_CT + (size_t)r * HH_);
    const floatx4* __restrict__ k4  = (const floatx4*)(gK + (size_t)b * HH_);
    const floatx4* __restrict__ q4  = (const floatx4*)(gQ + (size_t)b * HH_);

    float acc = 0.f;
#pragma unroll
    for (int jj = 0; jj < 4; ++jj) {
        const int idx = jj * 64 + lane;
        const floatx4 cv = __builtin_nontemporal_load(&c4[idx]);
        const floatx4 kv = k4[idx];
        const floatx4 qv = q4[idx];
        floatx4 o;
        o.x = ftv * cv.x + vtv * kv.x;
        o.y = ftv * cv.y + vtv * kv.y;
        o.z = ftv * cv.z + vtv * kv.z;
        o.w = ftv * cv.w + vtv * kv.w;
        __builtin_nontemporal_store(o, &ct4[idx]);
        acc += o.x * qv.x + o.y * qv.y + o.z * qv.z + o.w * qv.w;
    }

#pragma unroll
    for (int off = 32; off; off >>= 1)
        acc += __shfl_down(acc, off, 64);

    if (lane == 0)
        out[OFF_HT + r] = gO[r] * acc / dn;
}

// ---------------------------------------------------------------------------
extern "C" void kernel_launch(void* const* d_in, const int* in_sizes, int n_in,
                              void* d_out, int out_size, void* d_ws, size_t ws_size,
                              hipStream_t stream)
{
    const float* x = (const float*)d_in[0];
    const float* c = (const float*)d_in[1];
    const float* n = (const float*)d_in[2];
    const float* m = (const float*)d_in[3];
    const float* W[6];
    const float* bias[6];
    for (int i = 0; i < 6; ++i) W[i]    = (const float*)d_in[4 + i];
    for (int i = 0; i < 6; ++i) bias[i] = (const float*)d_in[10 + i];
    float* out = (float*)d_out;
    float* ws  = (float*)d_ws;

    int splitk = 8;
    {
        const size_t need = ((size_t)6 * splitk * BB_ * HH_ + 5 * (size_t)BB_ * HH_ + 64) * sizeof(float);
        if (ws_size < need) splitk = 1;   // compact fallback (~2.9 MB)
    }

    float* part  = ws;
    float* gF    = ws + (size_t)6 * splitk * BB_ * HH_;
    float* gV    = gF + (size_t)BB_ * HH_;
    float* gK    = gV + (size_t)BB_ * HH_;
    float* gQ    = gK + (size_t)BB_ * HH_;
    float* gO    = gQ + (size_t)BB_ * HH_;
    float* denom = gO + (size_t)BB_ * HH_;

    hipMemsetAsync(denom, 0, BB_ * sizeof(float), stream);

    proj_kernel<<<6 * splitk * 16, 256, 0, stream>>>(
        x, W[0], W[1], W[2], W[3], W[4], W[5], part, splitk);

    gate_kernel<<<dim3(HH_ / 256, BB_), 256, 0, stream>>>(
        part, bias[0], bias[1], bias[2], bias[3], bias[4], bias[5],
        n, m, out, gF, gV, gK, gQ, gO, denom, splitk);

    state_kernel<<<(BB_ * HH_) / 4, 256, 0, stream>>>(
        c, gF, gV, gK, gQ, gO, denom, out);
}